// Round 9
// baseline (283.028 us; speedup 1.0000x reference)
//
#include <hip/hip_runtime.h>

typedef __attribute__((ext_vector_type(4))) float f32x4;
typedef __attribute__((ext_vector_type(8))) short bf16x8;

__device__ inline ushort f2bf(float f) {
    uint u = __builtin_bit_cast(uint, f);
    u += 0x7fff + ((u >> 16) & 1);          // round-to-nearest-even
    return (ushort)(u >> 16);
}
__device__ inline float bf2f(ushort h) {
    uint u = ((uint)h) << 16;
    return __builtin_bit_cast(float, u);
}
__device__ inline uint packbf(float lo, float hi) {
    return (uint)f2bf(lo) | ((uint)f2bf(hi) << 16);
}

#define GRP 8          // XCD count; blockIdx.x & 7 ~ XCD id under round-robin dispatch
#define NSLICE 6250    // 50000 / 8 (dst nodes per partition)
#define CHUNK 2048     // edges per block-chunk in hist/fill

// ---------------- fused pre-pass: x->bf16 (packed), weights->bf16, dst histogram ----------------
__global__ __launch_bounds__(256) void k_pre(
    const float* __restrict__ x,
    const float* __restrict__ Wl1, const float* __restrict__ Wr1,
    const float* __restrict__ Wl2, const float* __restrict__ Wr2,
    const int* __restrict__ ei,
    ushort* __restrict__ A1x, ushort* __restrict__ W1cat, ushort* __restrict__ W2cat,
    int* __restrict__ cnt, int n, int nE, int nxb, int histBase)
{
    const int b = blockIdx.x;
    if (b < nxb) {
        int e4 = b * 256 + threadIdx.x;
        if (e4 >= n * 32) return;
        int i = e4 >> 5, c4 = e4 & 31;
        float4 v = *(const float4*)(x + (size_t)i * 128 + c4 * 4);
        ushort4 o;
        o.x = f2bf(v.x); o.y = f2bf(v.y); o.z = f2bf(v.z); o.w = f2bf(v.w);
        *(ushort4*)(A1x + (size_t)i * 128 + c4 * 4) = o;
        return;
    }
    if (b < nxb + 128) {
        int t = (b - nxb) * 256 + threadIdx.x;   // 0..32767
        int which = t >> 14;
        int r = (t >> 6) & 255;
        int kq = t & 63;
        const float* src;
        ushort* dst;
        if (which == 0) {
            src = (kq < 32) ? (Wl1 + (size_t)r * 128 + kq * 4)
                            : (Wr1 + (size_t)r * 128 + (kq - 32) * 4);
            dst = W1cat + (size_t)r * 256 + kq * 4;
        } else {
            src = (r < 128) ? (Wl2 + (size_t)r * 256 + kq * 4)
                            : (Wr2 + (size_t)(r - 128) * 256 + kq * 4);
            dst = W2cat + (size_t)r * 256 + kq * 4;
        }
        float4 v = *(const float4*)src;
        ushort4 o;
        o.x = f2bf(v.x); o.y = f2bf(v.y); o.z = f2bf(v.z); o.w = f2bf(v.w);
        *(ushort4*)dst = o;
        return;
    }
    if (b < histBase) return;
    const int hb = b - histBase;
    const int g = hb & 7;
    const int c = hb >> 3;
    const int lo = g * NSLICE, hi = lo + NSLICE;
    #pragma unroll
    for (int p = 0; p < CHUNK / 256; ++p) {
        int e = c * CHUNK + p * 256 + threadIdx.x;
        if (e < nE) {
            int d = ei[nE + e];
            if (d >= lo && d < hi) atomicAdd(&cnt[d], 1);
        }
    }
}

// ---------------- block-local exclusive scan ----------------
__global__ __launch_bounds__(1024) void k_scan1(const int* __restrict__ cnt,
                                                int* __restrict__ rp,
                                                int* __restrict__ bsum, int n) {
    __shared__ int buf[1024];
    const int tid = threadIdx.x;
    const int i = blockIdx.x * 1024 + tid;
    int v = (i < n) ? cnt[i] : 0;
    buf[tid] = v;
    __syncthreads();
    #pragma unroll
    for (int off = 1; off < 1024; off <<= 1) {
        int t = 0;
        if (tid >= off) t = buf[tid - off];
        __syncthreads();
        if (tid >= off) buf[tid] += t;
        __syncthreads();
    }
    if (i < n) rp[i] = buf[tid] - v;
    if (tid == 1023) bsum[blockIdx.x] = buf[1023];
}

// ---------------- scan3 with inlined top-level scan (nb <= 64) ----------------
__global__ __launch_bounds__(1024) void k_scan3b(int* __restrict__ rp,
                                                 const int* __restrict__ bsum,
                                                 int nb, int n) {
    __shared__ int sofs;
    if (threadIdx.x < 64) {
        int i = threadIdx.x;
        int v = (i < nb) ? bsum[i] : 0;
        int s = v;
        #pragma unroll
        for (int off = 1; off < 64; off <<= 1) {
            int t = __shfl_up(s, off, 64);
            if (i >= off) s += t;
        }
        if (i == (int)blockIdx.x) sofs = s - v;
        if ((int)blockIdx.x == nb - 1 && i == nb - 1) rp[n] = s;
    }
    __syncthreads();
    int i = blockIdx.x * 1024 + threadIdx.x;
    if (i < n) rp[i] += sofs;
}

// ---------------- XCD-partitioned counting-sort fill ----------------
__global__ __launch_bounds__(256) void k_fill_p(const int* __restrict__ ei,
                                                const int* __restrict__ rp,
                                                int* __restrict__ cur,
                                                int* __restrict__ srt, int nE) {
    const int g = blockIdx.x & 7;
    const int c = blockIdx.x >> 3;
    const int lo = g * NSLICE, hi = lo + NSLICE;
    #pragma unroll
    for (int p = 0; p < CHUNK / 256; ++p) {
        int e = c * CHUNK + p * 256 + threadIdx.x;
        if (e < nE) {
            int d = ei[nE + e];
            if (d >= lo && d < hi) {
                int s = ei[e];
                int pos = rp[d] + atomicAdd(&cur[d], 1);
                srt[pos] = s;
            }
        }
    }
}

// ---------------- fused gather1 + 2-layer MFMA GEMM ----------------
// Per 64-node block:
//   stage own x rows -> sA[:,256:512); gather neighbor means -> sA[:,0:256)
//   GEMM1: H = [mean|x] @ W1^T + b1 -> overwrites sA
//   GEMM2: [T2|Rb] = H @ W2^T -> global (packed 128-col arrays)
// 512 threads = 8 waves; W fragments hoisted to registers (L2 latency hidden
// under stage/gather). A/H in 32KB swizzled LDS (byte ^= (row&7)<<4).
__global__ __launch_bounds__(512) void k_gemm_fused(
    const ushort* __restrict__ A1x, const ushort* __restrict__ W1,
    const ushort* __restrict__ W2, const float* __restrict__ b1,
    const int* __restrict__ srt, const int* __restrict__ rp,
    ushort* __restrict__ T2, ushort* __restrict__ Rb, int n)
{
    __shared__ __align__(16) char sA[32768];   // 64 rows x 512 B, swizzled; reused for H
    const int bi = blockIdx.x * 64;
    const int tid = threadIdx.x;
    const int wid = tid >> 6;
    const int lane = tid & 63;
    const int wn = wid * 32;
    const int lr = lane & 15;
    const int lkb = (lane >> 4) * 16;
    const int quad = lane >> 4;
    const int col16 = (lane & 15) * 16;

    // ---- hoist W1 fragment loads (latency hides under stage+gather) ----
    bf16x8 w1r[16];
    #pragma unroll
    for (int kk = 0; kk < 8; ++kk)
        #pragma unroll
        for (int ni = 0; ni < 2; ++ni)
            w1r[kk * 2 + ni] = *(const bf16x8*)((const char*)W1 +
                (size_t)(wn + ni * 16 + lr) * 512 + kk * 64 + lkb);

    // ---- stage own x rows into sA[:,256:512) ----
    #pragma unroll
    for (int p = 0; p < 2; ++p) {
        const int idx = p * 512 + tid;       // 0..1023
        const int row = idx >> 4;
        const int cb = (idx & 15) * 16;
        uint4 v = *(const uint4*)((const char*)A1x + (size_t)(bi + row) * 256 + cb);
        *(uint4*)(sA + row * 512 + ((256 + cb) ^ ((row & 7) << 4))) = v;
    }

    // ---- gather neighbor means into sA[:,0:256): wave w owns nodes bi+w*8..+7 ----
    #pragma unroll 1
    for (int i = 0; i < 8; ++i) {
        const int row = wid * 8 + i;
        const int node = bi + row;
        if (node >= n) continue;
        const int beg = rp[node], end = rp[node + 1];
        float a0 = 0.f, a1 = 0.f, a2 = 0.f, a3 = 0.f;
        float a4 = 0.f, a5 = 0.f, a6 = 0.f, a7 = 0.f;
        for (int e = beg; e < end; e += 16) {
            uint4 v[4]; int live[4];
            #pragma unroll
            for (int q = 0; q < 4; ++q) {
                int idx = e + q * 4 + quad;
                live[q] = idx < end;
                int s = srt[live[q] ? idx : end - 1];
                v[q] = *(const uint4*)((const char*)A1x + (size_t)s * 256 + col16);
            }
            #pragma unroll
            for (int q = 0; q < 4; ++q) {
                if (live[q]) {
                    a0 += bf2f((ushort)v[q].x);  a1 += bf2f((ushort)(v[q].x >> 16));
                    a2 += bf2f((ushort)v[q].y);  a3 += bf2f((ushort)(v[q].y >> 16));
                    a4 += bf2f((ushort)v[q].z);  a5 += bf2f((ushort)(v[q].z >> 16));
                    a6 += bf2f((ushort)v[q].w);  a7 += bf2f((ushort)(v[q].w >> 16));
                }
            }
        }
        a0 += __shfl_xor(a0, 16); a1 += __shfl_xor(a1, 16);
        a2 += __shfl_xor(a2, 16); a3 += __shfl_xor(a3, 16);
        a4 += __shfl_xor(a4, 16); a5 += __shfl_xor(a5, 16);
        a6 += __shfl_xor(a6, 16); a7 += __shfl_xor(a7, 16);
        a0 += __shfl_xor(a0, 32); a1 += __shfl_xor(a1, 32);
        a2 += __shfl_xor(a2, 32); a3 += __shfl_xor(a3, 32);
        a4 += __shfl_xor(a4, 32); a5 += __shfl_xor(a5, 32);
        a6 += __shfl_xor(a6, 32); a7 += __shfl_xor(a7, 32);
        if (quad == 0) {
            const float invd = 1.0f / fmaxf((float)(end - beg), 1.0f);
            uint4 o;
            o.x = packbf(a0 * invd, a1 * invd);
            o.y = packbf(a2 * invd, a3 * invd);
            o.z = packbf(a4 * invd, a5 * invd);
            o.w = packbf(a6 * invd, a7 * invd);
            *(uint4*)(sA + row * 512 + (col16 ^ ((row & 7) << 4))) = o;
        }
    }
    __syncthreads();

    const int crow0 = (lane >> 4) * 4;
    const int ccol = lane & 15;

    // ---- GEMM 1: acc = [mean|x] @ W1^T ----
    f32x4 acc[4][2] = {};
    {
        // hoist W2 loads; latency hides under GEMM1 MFMAs
        bf16x8 w2r[16];
        #pragma unroll
        for (int kk = 0; kk < 8; ++kk)
            #pragma unroll
            for (int ni = 0; ni < 2; ++ni)
                w2r[kk * 2 + ni] = *(const bf16x8*)((const char*)W2 +
                    (size_t)(wn + ni * 16 + lr) * 512 + kk * 64 + lkb);

        #pragma unroll
        for (int kk = 0; kk < 8; ++kk) {
            bf16x8 af[4];
            #pragma unroll
            for (int mi = 0; mi < 4; ++mi) {
                const int row = mi * 16 + lr;
                af[mi] = *(const bf16x8*)(sA + row * 512 + ((kk * 64 + lkb) ^ ((row & 7) << 4)));
            }
            #pragma unroll
            for (int mi = 0; mi < 4; ++mi)
                #pragma unroll
                for (int ni = 0; ni < 2; ++ni)
                    acc[mi][ni] = __builtin_amdgcn_mfma_f32_16x16x32_bf16(
                        af[mi], w1r[kk * 2 + ni], acc[mi][ni], 0, 0, 0);
        }
        __syncthreads();   // all sA reads done; safe to overwrite with H

        {
            const float badd0 = b1[wn + ccol];
            const float badd1 = b1[wn + 16 + ccol];
            #pragma unroll
            for (int mi = 0; mi < 4; ++mi)
                #pragma unroll
                for (int ni = 0; ni < 2; ++ni) {
                    const int col = wn + ni * 16 + ccol;
                    const float badd = ni ? badd1 : badd0;
                    #pragma unroll
                    for (int j = 0; j < 4; ++j) {
                        const int row = mi * 16 + crow0 + j;
                        *(ushort*)(sA + row * 512 + ((col * 2) ^ ((row & 7) << 4))) =
                            f2bf(acc[mi][ni][j] + badd);
                    }
                }
        }
        __syncthreads();

        // ---- GEMM 2: [T2|Rb] = H @ W2^T ----
        f32x4 acc2[4][2] = {};
        #pragma unroll
        for (int kk = 0; kk < 8; ++kk) {
            bf16x8 af[4];
            #pragma unroll
            for (int mi = 0; mi < 4; ++mi) {
                const int row = mi * 16 + lr;
                af[mi] = *(const bf16x8*)(sA + row * 512 + ((kk * 64 + lkb) ^ ((row & 7) << 4)));
            }
            #pragma unroll
            for (int mi = 0; mi < 4; ++mi)
                #pragma unroll
                for (int ni = 0; ni < 2; ++ni)
                    acc2[mi][ni] = __builtin_amdgcn_mfma_f32_16x16x32_bf16(
                        af[mi], w2r[kk * 2 + ni], acc2[mi][ni], 0, 0, 0);
        }
        #pragma unroll
        for (int mi = 0; mi < 4; ++mi)
            #pragma unroll
            for (int ni = 0; ni < 2; ++ni) {
                const int ocol = wn + ni * 16 + ccol;
                ushort* dstbase = (ocol < 128) ? (T2 + ocol) : (Rb + ocol - 128);
                #pragma unroll
                for (int j = 0; j < 4; ++j) {
                    const int grow = bi + mi * 16 + crow0 + j;
                    if (grow < n)
                        dstbase[(size_t)grow * 128] = f2bf(acc2[mi][ni][j]);
                }
            }
    }
}

// ---------------- gather2 + finalize: out[i] = mean_{s} T2[s] + Rb[i] + b2 ----------------
__global__ __launch_bounds__(256) void k_gather2(const ushort* __restrict__ T2,
                                                 const ushort* __restrict__ Rb,
                                                 const int* __restrict__ srt,
                                                 const int* __restrict__ rp,
                                                 const float* __restrict__ b2,
                                                 float* __restrict__ out, int n) {
    const int node = blockIdx.x * 4 + (threadIdx.x >> 6);
    if (node >= n) return;
    const int lane = threadIdx.x & 63;
    const int quad = lane >> 4;
    const int col16 = (lane & 15) * 16;
    const int beg = rp[node], end = rp[node + 1];
    float a0 = 0.f, a1 = 0.f, a2 = 0.f, a3 = 0.f;
    float a4 = 0.f, a5 = 0.f, a6 = 0.f, a7 = 0.f;
    for (int e = beg; e < end; e += 16) {
        uint4 v[4]; int live[4];
        #pragma unroll
        for (int q = 0; q < 4; ++q) {
            int idx = e + q * 4 + quad;
            live[q] = idx < end;
            int s = srt[live[q] ? idx : end - 1];
            v[q] = *(const uint4*)((const char*)T2 + (size_t)s * 256 + col16);
        }
        #pragma unroll
        for (int q = 0; q < 4; ++q) {
            if (live[q]) {
                a0 += bf2f((ushort)v[q].x);  a1 += bf2f((ushort)(v[q].x >> 16));
                a2 += bf2f((ushort)v[q].y);  a3 += bf2f((ushort)(v[q].y >> 16));
                a4 += bf2f((ushort)v[q].z);  a5 += bf2f((ushort)(v[q].z >> 16));
                a6 += bf2f((ushort)v[q].w);  a7 += bf2f((ushort)(v[q].w >> 16));
            }
        }
    }
    a0 += __shfl_xor(a0, 16); a1 += __shfl_xor(a1, 16);
    a2 += __shfl_xor(a2, 16); a3 += __shfl_xor(a3, 16);
    a4 += __shfl_xor(a4, 16); a5 += __shfl_xor(a5, 16);
    a6 += __shfl_xor(a6, 16); a7 += __shfl_xor(a7, 16);
    a0 += __shfl_xor(a0, 32); a1 += __shfl_xor(a1, 32);
    a2 += __shfl_xor(a2, 32); a3 += __shfl_xor(a3, 32);
    a4 += __shfl_xor(a4, 32); a5 += __shfl_xor(a5, 32);
    a6 += __shfl_xor(a6, 32); a7 += __shfl_xor(a7, 32);
    if (quad == 0) {
        const float invd = 1.0f / fmaxf((float)(end - beg), 1.0f);
        uint4 rv = *(const uint4*)((const char*)Rb + (size_t)node * 256 + col16);
        const int c8 = (lane & 15) * 8;
        float4 bb0 = *(const float4*)(b2 + c8);
        float4 bb1 = *(const float4*)(b2 + c8 + 4);
        float4 r0, r1;
        r0.x = a0 * invd + bf2f((ushort)rv.x) + bb0.x;
        r0.y = a1 * invd + bf2f((ushort)(rv.x >> 16)) + bb0.y;
        r0.z = a2 * invd + bf2f((ushort)rv.y) + bb0.z;
        r0.w = a3 * invd + bf2f((ushort)(rv.y >> 16)) + bb0.w;
        r1.x = a4 * invd + bf2f((ushort)rv.z) + bb1.x;
        r1.y = a5 * invd + bf2f((ushort)(rv.z >> 16)) + bb1.y;
        r1.z = a6 * invd + bf2f((ushort)rv.w) + bb1.z;
        r1.w = a7 * invd + bf2f((ushort)(rv.w >> 16)) + bb1.w;
        *(float4*)(out + (size_t)node * 128 + c8) = r0;
        *(float4*)(out + (size_t)node * 128 + c8 + 4) = r1;
    }
}

extern "C" void kernel_launch(void* const* d_in, const int* in_sizes, int n_in,
                              void* d_out, int out_size, void* d_ws, size_t ws_size,
                              hipStream_t stream) {
    const float* x   = (const float*)d_in[0];
    const int*   ei  = (const int*)  d_in[1];
    const float* Wl1 = (const float*)d_in[2];
    const float* bl1 = (const float*)d_in[3];
    const float* Wr1 = (const float*)d_in[4];
    const float* Wl2 = (const float*)d_in[5];
    const float* bl2 = (const float*)d_in[6];
    const float* Wr2 = (const float*)d_in[7];
    float* out = (float*)d_out;

    const int nN = 50000;
    const int nE = in_sizes[1] / 2;   // 800000

    char* ws = (char*)d_ws;
    int*    rp    = (int*)   (ws);                              // (nN+1) ints
    int*    cnt   = (int*)   (ws + 262144);                     // nN ints
    int*    cur   = (int*)   (ws + 524288);                     // nN ints
    int*    bsum  = (int*)   (ws + 786432);
    int*    srt   = (int*)   (ws + (size_t)1 * (1 << 20));      // 3.2 MB
    ushort* W1cat = (ushort*)(ws + (size_t)5 * (1 << 20));      // 128 KB
    ushort* W2cat = (ushort*)(ws + (size_t)5 * (1 << 20) + 262144);
    ushort* A1x   = (ushort*)(ws + (size_t)6 * (1 << 20));      // 12.8 MB packed (+pad rows)
    ushort* T2    = (ushort*)(ws + (size_t)20 * (1 << 20));     // 12.8 MB packed
    ushort* Rb    = (ushort*)(ws + (size_t)34 * (1 << 20));     // 12.8 MB packed

    const int nb = (nN + 1023) / 1024;             // 49
    const int nChunks = (nE + CHUNK - 1) / CHUNK;  // 391
    const int nxb = (nN * 32 + 255) / 256;         // 6250
    const int histBase = (nxb + 128 + 7) & ~7;     // 6384, 8-aligned

    hipMemsetAsync(cnt, 0, 524288, stream);        // cnt + cur

    // ---- pre-pass: conversions + histogram (one launch) ----
    k_pre<<<histBase + nChunks * GRP, 256, 0, stream>>>(
        x, Wl1, Wr1, Wl2, Wr2, ei, A1x, W1cat, W2cat, cnt, nN, nE, nxb, histBase);

    // ---- CSR: scan + fill ----
    k_scan1<<<nb, 1024, 0, stream>>>(cnt, rp, bsum, nN);
    k_scan3b<<<nb, 1024, 0, stream>>>(rp, bsum, nb, nN);
    k_fill_p<<<nChunks * GRP, 256, 0, stream>>>(ei, rp, cur, srt, nE);

    // ---- fused: gather1 + dual-layer GEMM ----
    k_gemm_fused<<<(nN + 63) / 64, 512, 0, stream>>>(
        A1x, W1cat, W2cat, bl1, srt, rp, T2, Rb, nN);

    // ---- layer 2 aggregation + finalize ----
    k_gather2<<<(nN + 3) / 4, 256, 0, stream>>>(T2, Rb, srt, rp, bl2, out, nN);
}

// Round 10
// 261.377 us; speedup vs baseline: 1.0828x; 1.0828x over previous
//
#include <hip/hip_runtime.h>

typedef __attribute__((ext_vector_type(4))) float f32x4;
typedef __attribute__((ext_vector_type(8))) short bf16x8;

__device__ inline ushort f2bf(float f) {
    uint u = __builtin_bit_cast(uint, f);
    u += 0x7fff + ((u >> 16) & 1);          // round-to-nearest-even
    return (ushort)(u >> 16);
}
__device__ inline float bf2f(ushort h) {
    uint u = ((uint)h) << 16;
    return __builtin_bit_cast(float, u);
}
__device__ inline uint packbf(float lo, float hi) {
    return (uint)f2bf(lo) | ((uint)f2bf(hi) << 16);
}

#define GRP 8          // XCD count; blockIdx.x & 7 ~ XCD id under round-robin dispatch
#define NSLICE 6250    // 50000 / 8 (dst nodes per partition)
#define CHUNK 2048     // edges per block-chunk in hist/fill

// ---------------- fused pre-pass: x->bf16, weights->bf16, dst histogram ----------------
__global__ __launch_bounds__(256) void k_pre(
    const float* __restrict__ x,
    const float* __restrict__ Wl1, const float* __restrict__ Wr1,
    const float* __restrict__ Wl2, const float* __restrict__ Wr2,
    const int* __restrict__ ei,
    ushort* __restrict__ A1, ushort* __restrict__ W1cat, ushort* __restrict__ W2cat,
    int* __restrict__ cnt, int n, int nE, int nxb, int histBase)
{
    const int b = blockIdx.x;
    if (b < nxb) {
        int e4 = b * 256 + threadIdx.x;
        if (e4 >= n * 32) return;
        int i = e4 >> 5, c4 = e4 & 31;
        float4 v = *(const float4*)(x + (size_t)i * 128 + c4 * 4);
        ushort4 o;
        o.x = f2bf(v.x); o.y = f2bf(v.y); o.z = f2bf(v.z); o.w = f2bf(v.w);
        *(ushort4*)(A1 + (size_t)i * 256 + 128 + c4 * 4) = o;
        return;
    }
    if (b < nxb + 128) {
        int t = (b - nxb) * 256 + threadIdx.x;   // 0..32767
        int which = t >> 14;
        int r = (t >> 6) & 255;
        int kq = t & 63;
        const float* src;
        ushort* dst;
        if (which == 0) {
            src = (kq < 32) ? (Wl1 + (size_t)r * 128 + kq * 4)
                            : (Wr1 + (size_t)r * 128 + (kq - 32) * 4);
            dst = W1cat + (size_t)r * 256 + kq * 4;
        } else {
            src = (r < 128) ? (Wl2 + (size_t)r * 256 + kq * 4)
                            : (Wr2 + (size_t)(r - 128) * 256 + kq * 4);
            dst = W2cat + (size_t)r * 256 + kq * 4;
        }
        float4 v = *(const float4*)src;
        ushort4 o;
        o.x = f2bf(v.x); o.y = f2bf(v.y); o.z = f2bf(v.z); o.w = f2bf(v.w);
        *(ushort4*)dst = o;
        return;
    }
    if (b < histBase) return;
    const int hb = b - histBase;
    const int g = hb & 7;
    const int c = hb >> 3;
    const int lo = g * NSLICE, hi = lo + NSLICE;
    #pragma unroll
    for (int p = 0; p < CHUNK / 256; ++p) {
        int e = c * CHUNK + p * 256 + threadIdx.x;
        if (e < nE) {
            int d = ei[nE + e];
            if (d >= lo && d < hi) atomicAdd(&cnt[d], 1);
        }
    }
}

// ---------------- block-local exclusive scan ----------------
__global__ __launch_bounds__(1024) void k_scan1(const int* __restrict__ cnt,
                                                int* __restrict__ rp,
                                                int* __restrict__ bsum, int n) {
    __shared__ int buf[1024];
    const int tid = threadIdx.x;
    const int i = blockIdx.x * 1024 + tid;
    int v = (i < n) ? cnt[i] : 0;
    buf[tid] = v;
    __syncthreads();
    #pragma unroll
    for (int off = 1; off < 1024; off <<= 1) {
        int t = 0;
        if (tid >= off) t = buf[tid - off];
        __syncthreads();
        if (tid >= off) buf[tid] += t;
        __syncthreads();
    }
    if (i < n) rp[i] = buf[tid] - v;
    if (tid == 1023) bsum[blockIdx.x] = buf[1023];
}

// ---------------- scan3 with inlined top-level scan (nb <= 64) ----------------
__global__ __launch_bounds__(1024) void k_scan3b(int* __restrict__ rp,
                                                 const int* __restrict__ bsum,
                                                 int nb, int n) {
    __shared__ int sofs;
    if (threadIdx.x < 64) {
        int i = threadIdx.x;
        int v = (i < nb) ? bsum[i] : 0;
        int s = v;
        #pragma unroll
        for (int off = 1; off < 64; off <<= 1) {
            int t = __shfl_up(s, off, 64);
            if (i >= off) s += t;
        }
        if (i == (int)blockIdx.x) sofs = s - v;
        if ((int)blockIdx.x == nb - 1 && i == nb - 1) rp[n] = s;
    }
    __syncthreads();
    int i = blockIdx.x * 1024 + threadIdx.x;
    if (i < n) rp[i] += sofs;
}

// ---------------- XCD-partitioned counting-sort fill ----------------
__global__ __launch_bounds__(256) void k_fill_p(const int* __restrict__ ei,
                                                const int* __restrict__ rp,
                                                int* __restrict__ cur,
                                                int* __restrict__ srt, int nE) {
    const int g = blockIdx.x & 7;
    const int c = blockIdx.x >> 3;
    const int lo = g * NSLICE, hi = lo + NSLICE;
    #pragma unroll
    for (int p = 0; p < CHUNK / 256; ++p) {
        int e = c * CHUNK + p * 256 + threadIdx.x;
        if (e < nE) {
            int d = ei[nE + e];
            if (d >= lo && d < hi) {
                int s = ei[e];
                int pos = rp[d] + atomicAdd(&cur[d], 1);
                srt[pos] = s;
            }
        }
    }
}

// ---------------- gather1: A1[i][0:128) = mean_{s in N(i)} A1[s][128:256) ----------------
// 2 nodes per wave (lanes 0-31 / 32-63); within a half: 2 sixteen-lane quads read
// 2 edges per load inst; 4 insts = 8 edges/node/round (less clamp waste than 16).
__global__ __launch_bounds__(256) void k_gather1(ushort* A1,
                                                 const int* __restrict__ srt,
                                                 const int* __restrict__ rp, int n) {
    const int wav = blockIdx.x * 4 + (threadIdx.x >> 6);
    const int lane = threadIdx.x & 63;
    const int node = wav * 2 + (lane >> 5);
    if (node >= n) return;
    const int q2 = (lane >> 4) & 1;
    const int col16 = (lane & 15) * 16;
    const int beg = rp[node], end = rp[node + 1];
    float a0 = 0.f, a1 = 0.f, a2 = 0.f, a3 = 0.f;
    float a4 = 0.f, a5 = 0.f, a6 = 0.f, a7 = 0.f;
    for (int e = beg; e < end; e += 8) {
        uint4 v[4]; int live[4];
        #pragma unroll
        for (int q = 0; q < 4; ++q) {
            int idx = e + q * 2 + q2;
            live[q] = idx < end;
            int s = srt[live[q] ? idx : end - 1];
            v[q] = *(const uint4*)((const char*)A1 + (size_t)s * 512 + 256 + col16);
        }
        #pragma unroll
        for (int q = 0; q < 4; ++q) {
            if (live[q]) {
                a0 += bf2f((ushort)v[q].x);  a1 += bf2f((ushort)(v[q].x >> 16));
                a2 += bf2f((ushort)v[q].y);  a3 += bf2f((ushort)(v[q].y >> 16));
                a4 += bf2f((ushort)v[q].z);  a5 += bf2f((ushort)(v[q].z >> 16));
                a6 += bf2f((ushort)v[q].w);  a7 += bf2f((ushort)(v[q].w >> 16));
            }
        }
    }
    a0 += __shfl_xor(a0, 16); a1 += __shfl_xor(a1, 16);
    a2 += __shfl_xor(a2, 16); a3 += __shfl_xor(a3, 16);
    a4 += __shfl_xor(a4, 16); a5 += __shfl_xor(a5, 16);
    a6 += __shfl_xor(a6, 16); a7 += __shfl_xor(a7, 16);
    if (q2 == 0) {
        const float invd = 1.0f / fmaxf((float)(end - beg), 1.0f);
        uint4 o;
        o.x = packbf(a0 * invd, a1 * invd);
        o.y = packbf(a2 * invd, a3 * invd);
        o.z = packbf(a4 * invd, a5 * invd);
        o.w = packbf(a6 * invd, a7 * invd);
        *(uint4*)((char*)A1 + (size_t)node * 512 + col16) = o;
    }
}

// ---------------- gather2 + finalize: out[i] = mean(t2[nbrs]) + rbuf[i] + b2 ----------------
// H2 layout: [i][0:128)=t2 (bf16), [i][128:256)=rbuf (bf16)
__global__ __launch_bounds__(256) void k_gather2(const ushort* __restrict__ H2,
                                                 const int* __restrict__ srt,
                                                 const int* __restrict__ rp,
                                                 const float* __restrict__ b2,
                                                 float* __restrict__ out, int n) {
    const int wav = blockIdx.x * 4 + (threadIdx.x >> 6);
    const int lane = threadIdx.x & 63;
    const int node = wav * 2 + (lane >> 5);
    if (node >= n) return;
    const int q2 = (lane >> 4) & 1;
    const int col16 = (lane & 15) * 16;
    const int beg = rp[node], end = rp[node + 1];
    float a0 = 0.f, a1 = 0.f, a2 = 0.f, a3 = 0.f;
    float a4 = 0.f, a5 = 0.f, a6 = 0.f, a7 = 0.f;
    for (int e = beg; e < end; e += 8) {
        uint4 v[4]; int live[4];
        #pragma unroll
        for (int q = 0; q < 4; ++q) {
            int idx = e + q * 2 + q2;
            live[q] = idx < end;
            int s = srt[live[q] ? idx : end - 1];
            v[q] = *(const uint4*)((const char*)H2 + (size_t)s * 512 + col16);
        }
        #pragma unroll
        for (int q = 0; q < 4; ++q) {
            if (live[q]) {
                a0 += bf2f((ushort)v[q].x);  a1 += bf2f((ushort)(v[q].x >> 16));
                a2 += bf2f((ushort)v[q].y);  a3 += bf2f((ushort)(v[q].y >> 16));
                a4 += bf2f((ushort)v[q].z);  a5 += bf2f((ushort)(v[q].z >> 16));
                a6 += bf2f((ushort)v[q].w);  a7 += bf2f((ushort)(v[q].w >> 16));
            }
        }
    }
    a0 += __shfl_xor(a0, 16); a1 += __shfl_xor(a1, 16);
    a2 += __shfl_xor(a2, 16); a3 += __shfl_xor(a3, 16);
    a4 += __shfl_xor(a4, 16); a5 += __shfl_xor(a5, 16);
    a6 += __shfl_xor(a6, 16); a7 += __shfl_xor(a7, 16);
    if (q2 == 0) {
        const float invd = 1.0f / fmaxf((float)(end - beg), 1.0f);
        uint4 rv = *(const uint4*)((const char*)H2 + (size_t)node * 512 + 256 + col16);
        const int c8 = (lane & 15) * 8;
        float4 bb0 = *(const float4*)(b2 + c8);
        float4 bb1 = *(const float4*)(b2 + c8 + 4);
        float4 r0, r1;
        r0.x = a0 * invd + bf2f((ushort)rv.x) + bb0.x;
        r0.y = a1 * invd + bf2f((ushort)(rv.x >> 16)) + bb0.y;
        r0.z = a2 * invd + bf2f((ushort)rv.y) + bb0.z;
        r0.w = a3 * invd + bf2f((ushort)(rv.y >> 16)) + bb0.w;
        r1.x = a4 * invd + bf2f((ushort)rv.z) + bb1.x;
        r1.y = a5 * invd + bf2f((ushort)(rv.z >> 16)) + bb1.y;
        r1.z = a6 * invd + bf2f((ushort)rv.w) + bb1.z;
        r1.w = a7 * invd + bf2f((ushort)(rv.w >> 16)) + bb1.w;
        *(float4*)(out + (size_t)node * 128 + c8) = r0;
        *(float4*)(out + (size_t)node * 128 + c8 + 4) = r1;
    }
}

// ---------------- fused 2-layer MFMA GEMM, BM=128, W hoisted to registers ----------------
// __launch_bounds__(512,2): VGPR cap 256 so w1r[16]+w2r[16] (128 VGPR) stay resident;
// their L2 latency is issued as one batch and overlaps A-staging / GEMM1.
__global__ __launch_bounds__(512, 2) void k_gemm(
    const ushort* __restrict__ A, const ushort* __restrict__ W1,
    const ushort* __restrict__ W2, const float* __restrict__ b1,
    ushort* __restrict__ O, int n)
{
    __shared__ __align__(16) char sA[65536];   // 128 rows x 512 B, swizzled; reused for H
    const int bi = blockIdx.x * 128;
    const int tid = threadIdx.x;
    const int wid = tid >> 6;
    const int lane = tid & 63;
    const int wn = wid * 32;
    const int lr = lane & 15;
    const int lkb = (lane >> 4) * 16;

    // ---- hoist all W1 fragments (16 L2 loads issued back-to-back) ----
    bf16x8 w1r[16];
    #pragma unroll
    for (int kk = 0; kk < 8; ++kk)
        #pragma unroll
        for (int ni = 0; ni < 2; ++ni)
            w1r[kk * 2 + ni] = *(const bf16x8*)((const char*)W1 +
                (size_t)(wn + ni * 16 + lr) * 512 + kk * 64 + lkb);

    // ---- stage A-tile (64 KB): linear global read, swizzled LDS write ----
    #pragma unroll
    for (int p = 0; p < 8; ++p) {
        const int o = p * 8192 + tid * 16;
        const int row = o >> 9;
        const int cb = o & 511;
        uint4 v = *(const uint4*)((const char*)A + (size_t)(bi + row) * 512 + cb);
        *(uint4*)(sA + row * 512 + (cb ^ ((row & 7) << 4))) = v;
    }
    __syncthreads();

    // ---- hoist all W2 fragments (latency hides under GEMM1) ----
    bf16x8 w2r[16];
    #pragma unroll
    for (int kk = 0; kk < 8; ++kk)
        #pragma unroll
        for (int ni = 0; ni < 2; ++ni)
            w2r[kk * 2 + ni] = *(const bf16x8*)((const char*)W2 +
                (size_t)(wn + ni * 16 + lr) * 512 + kk * 64 + lkb);

    const int crow0 = (lane >> 4) * 4;
    const int ccol = lane & 15;

    // ---- GEMM 1: acc = [mean|x] @ W1^T ----
    f32x4 acc[8][2] = {};
    #pragma unroll
    for (int kk = 0; kk < 8; ++kk) {
        #pragma unroll
        for (int mi = 0; mi < 8; ++mi) {
            const int row = mi * 16 + lr;
            bf16x8 af = *(const bf16x8*)(sA + row * 512 + ((kk * 64 + lkb) ^ ((row & 7) << 4)));
            #pragma unroll
            for (int ni = 0; ni < 2; ++ni)
                acc[mi][ni] = __builtin_amdgcn_mfma_f32_16x16x32_bf16(
                    af, w1r[kk * 2 + ni], acc[mi][ni], 0, 0, 0);
        }
    }
    __syncthreads();   // all sA reads done; safe to overwrite with H

    {
        const float badd0 = b1[wn + ccol];
        const float badd1 = b1[wn + 16 + ccol];
        #pragma unroll
        for (int mi = 0; mi < 8; ++mi)
            #pragma unroll
            for (int ni = 0; ni < 2; ++ni) {
                const int col = wn + ni * 16 + ccol;
                const float badd = ni ? badd1 : badd0;
                #pragma unroll
                for (int j = 0; j < 4; ++j) {
                    const int row = mi * 16 + crow0 + j;
                    *(ushort*)(sA + row * 512 + ((col * 2) ^ ((row & 7) << 4))) =
                        f2bf(acc[mi][ni][j] + badd);
                }
            }
    }
    __syncthreads();

    // ---- GEMM 2: [T2|Rb] = H @ W2^T (acc reused) ----
    #pragma unroll
    for (int mi = 0; mi < 8; ++mi)
        #pragma unroll
        for (int ni = 0; ni < 2; ++ni)
            acc[mi][ni] = (f32x4){0.f, 0.f, 0.f, 0.f};
    #pragma unroll
    for (int kk = 0; kk < 8; ++kk) {
        #pragma unroll
        for (int mi = 0; mi < 8; ++mi) {
            const int row = mi * 16 + lr;
            bf16x8 af = *(const bf16x8*)(sA + row * 512 + ((kk * 64 + lkb) ^ ((row & 7) << 4)));
            #pragma unroll
            for (int ni = 0; ni < 2; ++ni)
                acc[mi][ni] = __builtin_amdgcn_mfma_f32_16x16x32_bf16(
                    af, w2r[kk * 2 + ni], acc[mi][ni], 0, 0, 0);
        }
    }
    #pragma unroll
    for (int mi = 0; mi < 8; ++mi)
        #pragma unroll
        for (int ni = 0; ni < 2; ++ni) {
            const int ocol = wn + ni * 16 + ccol;
            #pragma unroll
            for (int j = 0; j < 4; ++j) {
                const int grow = bi + mi * 16 + crow0 + j;
                if (grow < n)
                    O[(size_t)grow * 256 + ocol] = f2bf(acc[mi][ni][j]);
            }
        }
}

extern "C" void kernel_launch(void* const* d_in, const int* in_sizes, int n_in,
                              void* d_out, int out_size, void* d_ws, size_t ws_size,
                              hipStream_t stream) {
    const float* x   = (const float*)d_in[0];
    const int*   ei  = (const int*)  d_in[1];
    const float* Wl1 = (const float*)d_in[2];
    const float* bl1 = (const float*)d_in[3];
    const float* Wr1 = (const float*)d_in[4];
    const float* Wl2 = (const float*)d_in[5];
    const float* bl2 = (const float*)d_in[6];
    const float* Wr2 = (const float*)d_in[7];
    float* out = (float*)d_out;

    const int nN = 50000;
    const int nE = in_sizes[1] / 2;   // 800000

    char* ws = (char*)d_ws;
    int*    rp    = (int*)   (ws);                              // (nN+1) ints
    int*    cnt   = (int*)   (ws + 262144);                     // nN ints
    int*    cur   = (int*)   (ws + 524288);                     // nN ints
    int*    bsum  = (int*)   (ws + 786432);
    int*    srt   = (int*)   (ws + (size_t)1 * (1 << 20));      // 3.2 MB
    ushort* W1cat = (ushort*)(ws + (size_t)5 * (1 << 20));      // 128 KB
    ushort* W2cat = (ushort*)(ws + (size_t)5 * (1 << 20) + 262144);
    ushort* A1    = (ushort*)(ws + (size_t)6 * (1 << 20));      // 25.6 MB (+pad rows)
    ushort* H2    = (ushort*)(ws + (size_t)32 * (1 << 20));     // 25.6 MB (+pad rows)

    const int nb = (nN + 1023) / 1024;             // 49
    const int nChunks = (nE + CHUNK - 1) / CHUNK;  // 391
    const int nxb = (nN * 32 + 255) / 256;         // 6250
    const int histBase = (nxb + 128 + 7) & ~7;     // 6384, 8-aligned

    hipMemsetAsync(cnt, 0, 524288, stream);        // cnt + cur

    // ---- pre-pass: conversions + histogram (one launch) ----
    k_pre<<<histBase + nChunks * GRP, 256, 0, stream>>>(
        x, Wl1, Wr1, Wl2, Wr2, ei, A1, W1cat, W2cat, cnt, nN, nE, nxb, histBase);

    // ---- CSR: scan + fill ----
    k_scan1<<<nb, 1024, 0, stream>>>(cnt, rp, bsum, nN);
    k_scan3b<<<nb, 1024, 0, stream>>>(rp, bsum, nb, nN);
    k_fill_p<<<nChunks * GRP, 256, 0, stream>>>(ei, rp, cur, srt, nE);

    // ---- layer 1 aggregation, dual-layer GEMM, layer 2 aggregation ----
    k_gather1<<<(nN + 7) / 8, 256, 0, stream>>>(A1, srt, rp, nN);
    k_gemm<<<(nN + 127) / 128, 512, 0, stream>>>(A1, W1cat, W2cat, bl1, H2, nN);
    k_gather2<<<(nN + 7) / 8, 256, 0, stream>>>(H2, srt, rp, bl2, out, nN);
}